// Round 1
// baseline (806.334 us; speedup 1.0000x reference)
//
#include <hip/hip_runtime.h>
#include <math.h>

#define POOL 7
#define SR 2
#define NSAMP (POOL * POOL * SR * SR) // 196
#define NCH 256

// One block per box. Threads 0..195 precompute sample-point corner offsets and
// weights (shared across all channels) into LDS; then each of the 256 threads
// owns one channel and sweeps the 49 output cells (4 samples x 4 corners each).
__global__ __launch_bounds__(256) void roi_align_fpn_kernel(
    const float* __restrict__ p2, const float* __restrict__ p3,
    const float* __restrict__ p4, const float* __restrict__ p5,
    const float* __restrict__ boxes, const int* __restrict__ bidx,
    float* __restrict__ out, int N)
{
    int n = blockIdx.x;
    if (n >= N) return;

    __shared__ int   s_off[NSAMP][4];
    __shared__ float s_w[NSAMP][4];

    const int t = threadIdx.x;

    // ---- per-box params (computed redundantly by every thread; wave-uniform) ----
    float bx1 = boxes[4 * n + 0], by1 = boxes[4 * n + 1];
    float bx2 = boxes[4 * n + 2], by2 = boxes[4 * n + 3];
    float area = (by2 - by1) * (bx2 - bx1);
    // roi_level = clip(round(log2(sqrt(area))) + 4, 0, 3); rintf = round-half-even (matches jnp.round)
    float lvlf = logf(sqrtf(area)) * 1.4426950408889634f;
    int level = (int)fminf(fmaxf(rintf(lvlf) + 4.0f, 0.0f), 3.0f);

    int W = 256 >> level;          // levels are square: H == W (256,128,64,32)
    int H = W;
    int HW = W * W;
    float scale = (float)W;        // reference scales all 4 coords by f.shape[3]

    float x1 = bx1 * scale, y1 = by1 * scale;
    float x2 = bx2 * scale, y2 = by2 * scale;
    float roi_w = fmaxf(x2 - x1, 1.0f);
    float roi_h = fmaxf(y2 - y1, 1.0f);
    float bin_w = roi_w * (1.0f / POOL);
    float bin_h = roi_h * (1.0f / POOL);

    const float* feat = (level == 0) ? p2 : (level == 1) ? p3 : (level == 2) ? p4 : p5;
    int b = bidx[n];
    feat += (size_t)b * NCH * HW;

    // ---- precompute sample table ----
    if (t < NSAMP) {
        int cell = t >> 2;      // py*7 + px
        int samp = t & 3;       // sy*2 + sx
        int py = cell / POOL, px = cell % POOL;
        int sy = samp >> 1, sx = samp & 1;
        float offy = (float)py + ((float)sy + 0.5f) * 0.5f;
        float offx = (float)px + ((float)sx + 0.5f) * 0.5f;
        float y = y1 + bin_h * offy;
        float x = x1 + bin_w * offx;
        bool vy = (y > -1.0f) && (y < (float)H);
        bool vx = (x > -1.0f) && (x < (float)W);
        float yc = fminf(fmaxf(y, 0.0f), (float)(H - 1));
        float xc = fminf(fmaxf(x, 0.0f), (float)(W - 1));
        int ylo = (int)floorf(yc);
        int xlo = (int)floorf(xc);
        int yhi = min(ylo + 1, H - 1);
        int xhi = min(xlo + 1, W - 1);
        float fy = yc - (float)ylo;
        float fx = xc - (float)xlo;
        float v = (vy && vx) ? 0.25f : 0.0f;   // fold validity + 1/(SR*SR) mean into weights
        float hy = (1.0f - fy) * v, ly = fy * v;
        float hx = 1.0f - fx,      lx = fx;
        s_off[t][0] = ylo * W + xlo;
        s_off[t][1] = ylo * W + xhi;
        s_off[t][2] = yhi * W + xlo;
        s_off[t][3] = yhi * W + xhi;
        s_w[t][0] = hy * hx;
        s_w[t][1] = hy * lx;
        s_w[t][2] = ly * hx;
        s_w[t][3] = ly * lx;
    }
    __syncthreads();

    // ---- channel sweep: thread t = channel t ----
    const float* f = feat + (size_t)t * HW;
    float* o = out + ((size_t)n * NCH + t) * (POOL * POOL);
    for (int cell = 0; cell < POOL * POOL; ++cell) {
        float acc = 0.0f;
#pragma unroll
        for (int s = 0; s < 4; ++s) {
            int i = cell * 4 + s;
            acc += s_w[i][0] * f[s_off[i][0]]
                 + s_w[i][1] * f[s_off[i][1]]
                 + s_w[i][2] * f[s_off[i][2]]
                 + s_w[i][3] * f[s_off[i][3]];
        }
        o[cell] = acc;
    }
}

extern "C" void kernel_launch(void* const* d_in, const int* in_sizes, int n_in,
                              void* d_out, int out_size, void* d_ws, size_t ws_size,
                              hipStream_t stream) {
    const float* p2    = (const float*)d_in[0];
    const float* p3    = (const float*)d_in[1];
    const float* p4    = (const float*)d_in[2];
    const float* p5    = (const float*)d_in[3];
    const float* boxes = (const float*)d_in[4];
    const int*   bidx  = (const int*)d_in[5];
    float* out = (float*)d_out;
    int N = in_sizes[5];
    roi_align_fpn_kernel<<<N, 256, 0, stream>>>(p2, p3, p4, p5, boxes, bidx, out, N);
}

// Round 2
// 362.282 us; speedup vs baseline: 2.2257x; 2.2257x over previous
//
#include <hip/hip_runtime.h>
#include <math.h>

#define POOL 7
#define NCELL 49          // POOL*POOL
#define NCH 256
#define CH_SPLIT 2        // blocks per box (grid.y); each block covers NCH/CH_SPLIT channels

// One block-column per box. Within a wave: lane = output cell (49 active),
// wave iterates over channels. Sample-corner offsets & weights live in
// registers (computed once per lane, reused for all channels). Loads from a
// given instruction stay inside the box's ~20x20 feature window -> few cache
// lines, L1-resident. Stores are 196 contiguous bytes per wave.
__global__ __launch_bounds__(256) void roi_align_fpn_kernel(
    const float* __restrict__ p2, const float* __restrict__ p3,
    const float* __restrict__ p4, const float* __restrict__ p5,
    const float* __restrict__ boxes, const int* __restrict__ bidx,
    float* __restrict__ out, int N)
{
    const int n = blockIdx.x;
    if (n >= N) return;
    const int t = threadIdx.x;
    const int wave = t >> 6;     // 0..3
    const int lane = t & 63;

    // ---- per-box params (block-uniform; compiler scalarizes) ----
    float bx1 = boxes[4 * n + 0], by1 = boxes[4 * n + 1];
    float bx2 = boxes[4 * n + 2], by2 = boxes[4 * n + 3];
    float area = (by2 - by1) * (bx2 - bx1);
    float lvlf = logf(sqrtf(area)) * 1.4426950408889634f; // log2(sqrt(area))
    int level = (int)fminf(fmaxf(rintf(lvlf) + 4.0f, 0.0f), 3.0f);

    int W = 256 >> level;        // square levels: H == W
    int HW = W * W;
    float scale = (float)W;
    float x1 = bx1 * scale, y1 = by1 * scale;
    float x2 = bx2 * scale, y2 = by2 * scale;
    float bin_w = fmaxf(x2 - x1, 1.0f) * (1.0f / POOL);
    float bin_h = fmaxf(y2 - y1, 1.0f) * (1.0f / POOL);

    const float* feat = (level == 0) ? p2 : (level == 1) ? p3 : (level == 2) ? p4 : p5;
    feat += (size_t)bidx[n] * NCH * HW;

    // ---- per-lane sample table (registers): 4 samples x 4 corners ----
    int cell = (lane < NCELL) ? lane : (NCELL - 1);  // extra lanes mirror cell 48 (coalesce, no store)
    int py = cell / POOL, px = cell % POOL;

    int   off[4][4];
    float wgt[4][4];
#pragma unroll
    for (int s = 0; s < 4; ++s) {
        int sy = s >> 1, sx = s & 1;
        float y = y1 + bin_h * ((float)py + ((float)sy + 0.5f) * 0.5f);
        float x = x1 + bin_w * ((float)px + ((float)sx + 0.5f) * 0.5f);
        bool v = (y > -1.0f) && (y < (float)W) && (x > -1.0f) && (x < (float)W);
        float yc = fminf(fmaxf(y, 0.0f), (float)(W - 1));
        float xc = fminf(fmaxf(x, 0.0f), (float)(W - 1));
        int ylo = (int)floorf(yc), xlo = (int)floorf(xc);
        int yhi = min(ylo + 1, W - 1), xhi = min(xlo + 1, W - 1);
        float fy = yc - (float)ylo, fx = xc - (float)xlo;
        float vv = v ? 0.25f : 0.0f;                 // validity + 1/(SR*SR) mean folded in
        float hy = (1.0f - fy) * vv, ly = fy * vv;
        float hx = 1.0f - fx, lx = fx;
        off[s][0] = ylo * W + xlo; off[s][1] = ylo * W + xhi;
        off[s][2] = yhi * W + xlo; off[s][3] = yhi * W + xhi;
        wgt[s][0] = hy * hx; wgt[s][1] = hy * lx;
        wgt[s][2] = ly * hx; wgt[s][3] = ly * lx;
    }

    // ---- channel sweep: wave w of block y handles ch = y*128 + i*4 + w ----
    const int ch_base = blockIdx.y * (NCH / CH_SPLIT);
#pragma unroll 2
    for (int i = 0; i < NCH / (CH_SPLIT * 4); ++i) { // 32 iters
        int ch = ch_base + i * 4 + wave;
        const float* f = feat + (size_t)ch * HW;
        float acc = 0.0f;
#pragma unroll
        for (int s = 0; s < 4; ++s) {
            acc += wgt[s][0] * f[off[s][0]] + wgt[s][1] * f[off[s][1]]
                 + wgt[s][2] * f[off[s][2]] + wgt[s][3] * f[off[s][3]];
        }
        if (lane < NCELL)
            out[((size_t)n * NCH + ch) * NCELL + cell] = acc;
    }
}

extern "C" void kernel_launch(void* const* d_in, const int* in_sizes, int n_in,
                              void* d_out, int out_size, void* d_ws, size_t ws_size,
                              hipStream_t stream) {
    const float* p2    = (const float*)d_in[0];
    const float* p3    = (const float*)d_in[1];
    const float* p4    = (const float*)d_in[2];
    const float* p5    = (const float*)d_in[3];
    const float* boxes = (const float*)d_in[4];
    const int*   bidx  = (const int*)d_in[5];
    float* out = (float*)d_out;
    int N = in_sizes[5];
    dim3 grid(N, CH_SPLIT);
    roi_align_fpn_kernel<<<grid, 256, 0, stream>>>(p2, p3, p4, p5, boxes, bidx, out, N);
}

// Round 3
// 298.943 us; speedup vs baseline: 2.6973x; 1.2119x over previous
//
#include <hip/hip_runtime.h>
#include <math.h>

#define POOL 7
#define NCELL 49          // POOL*POOL
#define NCH 256
#define CH_SPLIT 4        // blocks per box (grid.y); each block covers NCH/CH_SPLIT channels

// float2 with 4-byte alignment promise: x_lo is arbitrary parity, so the
// row-pair load is only 4B-aligned. gfx950 supports unaligned global loads;
// declaring align(4) keeps the compiler honest either way.
typedef float v2f __attribute__((ext_vector_type(2), aligned(4)));

// One block-column per box. lane = output cell (49 active), wave iterates over
// channels. Per sample, the (x_lo, x_hi) corner pair is one float2 load (x_hi
// = x_lo+1; right-edge clamp folded into pair weights). 8 float2 loads per
// channel, all inside the box's small feature window -> L1/L2 resident.
__global__ __launch_bounds__(256) void roi_align_fpn_kernel(
    const float* __restrict__ p2, const float* __restrict__ p3,
    const float* __restrict__ p4, const float* __restrict__ p5,
    const float* __restrict__ boxes, const int* __restrict__ bidx,
    float* __restrict__ out, int N)
{
    const int n = blockIdx.x;
    if (n >= N) return;
    const int t = threadIdx.x;
    const int wave = t >> 6;     // 0..3
    const int lane = t & 63;

    // ---- per-box params (block-uniform) ----
    float bx1 = boxes[4 * n + 0], by1 = boxes[4 * n + 1];
    float bx2 = boxes[4 * n + 2], by2 = boxes[4 * n + 3];
    float area = (by2 - by1) * (bx2 - bx1);
    float lvlf = logf(sqrtf(area)) * 1.4426950408889634f; // log2(sqrt(area))
    int level = (int)fminf(fmaxf(rintf(lvlf) + 4.0f, 0.0f), 3.0f);

    int W = 256 >> level;        // square levels: H == W
    int HW = W * W;
    float scale = (float)W;
    float x1 = bx1 * scale, y1 = by1 * scale;
    float x2 = bx2 * scale, y2 = by2 * scale;
    float bin_w = fmaxf(x2 - x1, 1.0f) * (1.0f / POOL);
    float bin_h = fmaxf(y2 - y1, 1.0f) * (1.0f / POOL);

    const float* feat = (level == 0) ? p2 : (level == 1) ? p3 : (level == 2) ? p4 : p5;
    feat += (size_t)bidx[n] * NCH * HW;

    // ---- per-lane sample table (registers): 4 samples x 2 row-pairs ----
    int cell = (lane < NCELL) ? lane : (NCELL - 1);  // spare lanes mirror cell 48 (no store)
    int py = cell / POOL, px = cell % POOL;

    int   obase[4][2];   // [sample][row] element index of the float2 pair
    float wrow[4][2];    // row weights (validity * 0.25 folded in)
    float wx0[4], wx1[4]; // pair-position weights
#pragma unroll
    for (int s = 0; s < 4; ++s) {
        int sy = s >> 1, sx = s & 1;
        float y = y1 + bin_h * ((float)py + ((float)sy + 0.5f) * 0.5f);
        float x = x1 + bin_w * ((float)px + ((float)sx + 0.5f) * 0.5f);
        bool v = (y > -1.0f) && (y < (float)W) && (x > -1.0f) && (x < (float)W);
        float yc = fminf(fmaxf(y, 0.0f), (float)(W - 1));
        float xc = fminf(fmaxf(x, 0.0f), (float)(W - 1));
        int ylo = (int)floorf(yc), xlo = (int)floorf(xc);
        int yhi = min(ylo + 1, W - 1);
        float fy = yc - (float)ylo, fx = xc - (float)xlo;
        float vv = v ? 0.25f : 0.0f;                 // validity + 1/(SR*SR) mean
        // pair base: clamp so pair stays in-row; clamped case puts full weight on slot 1
        int bxp = min(xlo, W - 2);
        bool in = (xlo == bxp);
        wx0[s] = in ? (1.0f - fx) : 0.0f;
        wx1[s] = in ? fx : 1.0f;
        wrow[s][0] = (1.0f - fy) * vv;
        wrow[s][1] = fy * vv;
        obase[s][0] = ylo * W + bxp;
        obase[s][1] = yhi * W + bxp;
    }

    // ---- channel sweep: wave w handles ch = base + i*4 + w ----
    const int ch_base = blockIdx.y * (NCH / CH_SPLIT);
#pragma unroll 2
    for (int i = 0; i < NCH / (CH_SPLIT * 4); ++i) { // 16 iters
        int ch = ch_base + i * 4 + wave;
        const float* f = feat + (size_t)ch * HW;
        float acc = 0.0f;
#pragma unroll
        for (int s = 0; s < 4; ++s) {
            v2f r0 = *(const v2f*)(f + obase[s][0]);
            v2f r1 = *(const v2f*)(f + obase[s][1]);
            acc += wrow[s][0] * (wx0[s] * r0.x + wx1[s] * r0.y)
                 + wrow[s][1] * (wx0[s] * r1.x + wx1[s] * r1.y);
        }
        if (lane < NCELL)
            out[((size_t)n * NCH + ch) * NCELL + cell] = acc;
    }
}

extern "C" void kernel_launch(void* const* d_in, const int* in_sizes, int n_in,
                              void* d_out, int out_size, void* d_ws, size_t ws_size,
                              hipStream_t stream) {
    const float* p2    = (const float*)d_in[0];
    const float* p3    = (const float*)d_in[1];
    const float* p4    = (const float*)d_in[2];
    const float* p5    = (const float*)d_in[3];
    const float* boxes = (const float*)d_in[4];
    const int*   bidx  = (const int*)d_in[5];
    float* out = (float*)d_out;
    int N = in_sizes[5];
    dim3 grid(N, CH_SPLIT);
    roi_align_fpn_kernel<<<grid, 256, 0, stream>>>(p2, p3, p4, p5, boxes, bidx, out, N);
}

// Round 4
// 298.923 us; speedup vs baseline: 2.6975x; 1.0001x over previous
//
#include <hip/hip_runtime.h>
#include <math.h>

#define POOL 7
#define NCELL 49          // POOL*POOL
#define NCH 256
#define CH_SPLIT 8        // blocks per box; each block covers NCH/CH_SPLIT = 32 channels

// 8B load with 4B alignment promise (x_lo has arbitrary parity).
typedef float v2f __attribute__((ext_vector_type(2), aligned(4)));

// One block-column per box. lane = output cell (49 active), wave sweeps its
// channels two-at-a-time: all 16 row-pair loads issued before the FMA chains
// (16 outstanding VMEM per wave), separate accumulators. Output stores are
// non-temporal: the 50 MB output is write-once and must not evict feature
// window lines from L2/L3.
__global__ __launch_bounds__(256) void roi_align_fpn_kernel(
    const float* __restrict__ p2, const float* __restrict__ p3,
    const float* __restrict__ p4, const float* __restrict__ p5,
    const float* __restrict__ boxes, const int* __restrict__ bidx,
    float* __restrict__ out, int N)
{
    const int n = blockIdx.x;
    if (n >= N) return;
    const int t = threadIdx.x;
    const int wave = t >> 6;     // 0..3
    const int lane = t & 63;

    // ---- per-box params (block-uniform) ----
    float bx1 = boxes[4 * n + 0], by1 = boxes[4 * n + 1];
    float bx2 = boxes[4 * n + 2], by2 = boxes[4 * n + 3];
    float area = (by2 - by1) * (bx2 - bx1);
    float lvlf = logf(sqrtf(area)) * 1.4426950408889634f; // log2(sqrt(area))
    int level = (int)fminf(fmaxf(rintf(lvlf) + 4.0f, 0.0f), 3.0f);

    int W = 256 >> level;        // square levels: H == W
    int HW = W * W;
    float scale = (float)W;
    float x1 = bx1 * scale, y1 = by1 * scale;
    float x2 = bx2 * scale, y2 = by2 * scale;
    float bin_w = fmaxf(x2 - x1, 1.0f) * (1.0f / POOL);
    float bin_h = fmaxf(y2 - y1, 1.0f) * (1.0f / POOL);

    const float* feat = (level == 0) ? p2 : (level == 1) ? p3 : (level == 2) ? p4 : p5;
    feat += (size_t)bidx[n] * NCH * HW;

    // ---- per-lane sample table (registers): 4 samples x 2 row-pairs ----
    int cell = (lane < NCELL) ? lane : (NCELL - 1);  // spare lanes mirror cell 48 (no store)
    int py = cell / POOL, px = cell % POOL;

    int   obase[4][2];    // [sample][row] element index of the float2 pair
    float wrow[4][2];     // row weights (validity * 0.25 folded in)
    float wx0[4], wx1[4]; // pair-position weights
#pragma unroll
    for (int s = 0; s < 4; ++s) {
        int sy = s >> 1, sx = s & 1;
        float y = y1 + bin_h * ((float)py + ((float)sy + 0.5f) * 0.5f);
        float x = x1 + bin_w * ((float)px + ((float)sx + 0.5f) * 0.5f);
        bool v = (y > -1.0f) && (y < (float)W) && (x > -1.0f) && (x < (float)W);
        float yc = fminf(fmaxf(y, 0.0f), (float)(W - 1));
        float xc = fminf(fmaxf(x, 0.0f), (float)(W - 1));
        int ylo = (int)floorf(yc), xlo = (int)floorf(xc);
        int yhi = min(ylo + 1, W - 1);
        float fy = yc - (float)ylo, fx = xc - (float)xlo;
        float vv = v ? 0.25f : 0.0f;                 // validity + 1/(SR*SR) mean
        int bxp = min(xlo, W - 2);                   // keep pair in-row
        bool in = (xlo == bxp);
        wx0[s] = in ? (1.0f - fx) : 0.0f;
        wx1[s] = in ? fx : 1.0f;
        wrow[s][0] = (1.0f - fy) * vv;
        wrow[s][1] = fy * vv;
        obase[s][0] = ylo * W + bxp;
        obase[s][1] = yhi * W + bxp;
    }

    // ---- channel sweep: wave w, dual-channel software pipeline ----
    const int ch_base = blockIdx.y * (NCH / CH_SPLIT);
    const size_t out_base = (size_t)n * NCH * NCELL + cell;
#pragma unroll
    for (int i = 0; i < NCH / (CH_SPLIT * 4 * 2); ++i) { // 4 iters x 2 channels
        int chA = ch_base + (2 * i) * 4 + wave;
        int chB = chA + 4;
        const float* fA = feat + (size_t)chA * HW;
        const float* fB = feat + (size_t)chB * HW;
        v2f rA[4][2], rB[4][2];
#pragma unroll
        for (int s = 0; s < 4; ++s) {
            rA[s][0] = *(const v2f*)(fA + obase[s][0]);
            rA[s][1] = *(const v2f*)(fA + obase[s][1]);
        }
#pragma unroll
        for (int s = 0; s < 4; ++s) {
            rB[s][0] = *(const v2f*)(fB + obase[s][0]);
            rB[s][1] = *(const v2f*)(fB + obase[s][1]);
        }
        float accA = 0.0f, accB = 0.0f;
#pragma unroll
        for (int s = 0; s < 4; ++s) {
            accA += wrow[s][0] * (wx0[s] * rA[s][0].x + wx1[s] * rA[s][0].y)
                  + wrow[s][1] * (wx0[s] * rA[s][1].x + wx1[s] * rA[s][1].y);
            accB += wrow[s][0] * (wx0[s] * rB[s][0].x + wx1[s] * rB[s][0].y)
                  + wrow[s][1] * (wx0[s] * rB[s][1].x + wx1[s] * rB[s][1].y);
        }
        if (lane < NCELL) {
            __builtin_nontemporal_store(accA, out + out_base + (size_t)chA * NCELL);
            __builtin_nontemporal_store(accB, out + out_base + (size_t)chB * NCELL);
        }
    }
}

extern "C" void kernel_launch(void* const* d_in, const int* in_sizes, int n_in,
                              void* d_out, int out_size, void* d_ws, size_t ws_size,
                              hipStream_t stream) {
    const float* p2    = (const float*)d_in[0];
    const float* p3    = (const float*)d_in[1];
    const float* p4    = (const float*)d_in[2];
    const float* p5    = (const float*)d_in[3];
    const float* boxes = (const float*)d_in[4];
    const int*   bidx  = (const int*)d_in[5];
    float* out = (float*)d_out;
    int N = in_sizes[5];
    dim3 grid(N, CH_SPLIT);
    roi_align_fpn_kernel<<<grid, 256, 0, stream>>>(p2, p3, p4, p5, boxes, bidx, out, N);
}

// Round 5
// 285.366 us; speedup vs baseline: 2.8256x; 1.0475x over previous
//
#include <hip/hip_runtime.h>
#include <math.h>

#define POOL 7
#define NCELL 49
#define NCH 256
#define CH_SPLIT 4            // 4000 blocks; 64 ch/block, 16 ch/wave
#define CHPB (NCH / CH_SPLIT)
#define CHPW (CHPB / 4)
#define LDSF 640              // floats per wave window buffer (window packed <= ~601)
#define NIT 10                // staging iters: 10*64 = 640

// One block-column per box; wave = private 16-channel slice + private LDS
// window buffer (no __syncthreads anywhere). Per channel: <=10 coalesced
// staging loads (each window cache line touched once) -> LDS, then 49 lanes
// do the 16 bilinear taps from LDS. This replaces the 8 highly-divergent
// global gathers/channel (~130 L1 line-transactions) with ~35.
__global__ __launch_bounds__(256) void roi_align_fpn_kernel(
    const float* __restrict__ p2, const float* __restrict__ p3,
    const float* __restrict__ p4, const float* __restrict__ p5,
    const float* __restrict__ boxes, const int* __restrict__ bidx,
    float* __restrict__ out, int N)
{
    __shared__ float smem[4][LDSF];
    const int n = blockIdx.x;
    if (n >= N) return;
    const int t = threadIdx.x;
    const int wave = t >> 6;
    const int lane = t & 63;

    // ---- per-box params (block-uniform) ----
    float bx1 = boxes[4 * n + 0], by1 = boxes[4 * n + 1];
    float bx2 = boxes[4 * n + 2], by2 = boxes[4 * n + 3];
    float area = (by2 - by1) * (bx2 - bx1);
    float lvlf = logf(sqrtf(area)) * 1.4426950408889634f; // log2(sqrt(area))
    int level = (int)fminf(fmaxf(rintf(lvlf) + 4.0f, 0.0f), 3.0f);
    int W = 256 >> level;        // square levels
    int HW = W * W;
    float scale = (float)W;
    float x1 = bx1 * scale, y1 = by1 * scale;
    float bin_w = fmaxf((bx2 - bx1) * scale, 1.0f) * (1.0f / POOL);
    float bin_h = fmaxf((by2 - by1) * scale, 1.0f) * (1.0f / POOL);

    const float* feat = (level == 0) ? p2 : (level == 1) ? p3 : (level == 2) ? p4 : p5;
    feat += (size_t)bidx[n] * NCH * HW;

    // ---- window bounds (block-uniform; samples are monotonic in py/px) ----
    float yA = y1 + bin_h * 0.25f, yB = y1 + bin_h * 6.75f;
    float xA = x1 + bin_w * 0.25f, xB = x1 + bin_w * 6.75f;
    int y0  = (int)floorf(fminf(fmaxf(yA, 0.f), (float)(W - 1)));
    int y1h = min((int)floorf(fminf(fmaxf(yB, 0.f), (float)(W - 1))) + 1, W - 1);
    int x0  = (int)floorf(fminf(fmaxf(xA, 0.f), (float)(W - 1)));
    x0 = min(x0, W - 2);                       // pair base can be one left of first xlo
    int x1p = min((int)floorf(fminf(fmaxf(xB, 0.f), (float)(W - 1))) + 1, W - 1);
    int ww = x1p - x0 + 1;
    int wh = y1h - y0 + 1;
    wh = min(wh, LDSF / ww);                   // provably a no-op; memory-safety clamp
    int packed = ww * wh;

    // ---- staging address table (per lane, reused for all channels) ----
    int g_off[NIT];
#pragma unroll
    for (int k = 0; k < NIT; ++k) {
        int idx = k * 64 + lane;
        idx = (idx < packed) ? idx : 0;        // spare slots duplicate elem 0 (1 extra line)
        int r = idx / ww;
        int c = idx - r * ww;
        g_off[k] = (y0 + r) * W + (x0 + c);
    }

    // ---- per-lane sample tables: LDS offsets + pre-multiplied weights ----
    int cell = (lane < NCELL) ? lane : (NCELL - 1);
    int py = cell / POOL, px = cell % POOL;
    int loff0[4], loff1[4];
    float w00[4], w01[4], w10[4], w11[4];
#pragma unroll
    for (int s = 0; s < 4; ++s) {
        int sy = s >> 1, sx = s & 1;
        float y = y1 + bin_h * ((float)py + ((float)sy + 0.5f) * 0.5f);
        float x = x1 + bin_w * ((float)px + ((float)sx + 0.5f) * 0.5f);
        bool v = (y > -1.f) && (y < (float)W) && (x > -1.f) && (x < (float)W);
        float yc = fminf(fmaxf(y, 0.f), (float)(W - 1));
        float xc = fminf(fmaxf(x, 0.f), (float)(W - 1));
        int ylo = (int)floorf(yc), xlo = (int)floorf(xc);
        int yhi = min(ylo + 1, W - 1);
        float fy = yc - (float)ylo, fx = xc - (float)xlo;
        float vv = v ? 0.25f : 0.f;            // validity + 1/(SR*SR)
        int bxp = min(xlo, W - 2);             // keep float-pair in-row
        bool in = (xlo == bxp);
        float wx0 = in ? (1.f - fx) : 0.f;
        float wx1 = in ? fx : 1.f;
        float wr0 = (1.f - fy) * vv, wr1 = fy * vv;
        loff0[s] = (ylo - y0) * ww + (bxp - x0);
        loff1[s] = (yhi - y0) * ww + (bxp - x0);
        w00[s] = wr0 * wx0; w01[s] = wr0 * wx1;
        w10[s] = wr1 * wx0; w11[s] = wr1 * wx1;
    }

    // ---- channel sweep: wave-private LDS buffer, no barriers ----
    float* sm = smem[wave];
    const int ch0 = blockIdx.y * CHPB + wave * CHPW;
    const float* f = feat + (size_t)ch0 * HW;
    size_t obase = (size_t)n * NCH * NCELL + (size_t)ch0 * NCELL + cell;
#pragma unroll 2
    for (int i = 0; i < CHPW; ++i) {
        const float* fc = f + (size_t)i * HW;
        float g[NIT];
#pragma unroll
        for (int k = 0; k < NIT; ++k) g[k] = fc[g_off[k]];
#pragma unroll
        for (int k = 0; k < NIT; ++k) sm[k * 64 + lane] = g[k];
        float acc = 0.f;
#pragma unroll
        for (int s = 0; s < 4; ++s) {
            float a0 = sm[loff0[s]], a1 = sm[loff0[s] + 1];
            float b0 = sm[loff1[s]], b1 = sm[loff1[s] + 1];
            acc += w00[s] * a0 + w01[s] * a1 + w10[s] * b0 + w11[s] * b1;
        }
        if (lane < NCELL)
            __builtin_nontemporal_store(acc, out + obase + (size_t)i * NCELL);
    }
}

extern "C" void kernel_launch(void* const* d_in, const int* in_sizes, int n_in,
                              void* d_out, int out_size, void* d_ws, size_t ws_size,
                              hipStream_t stream) {
    const float* p2    = (const float*)d_in[0];
    const float* p3    = (const float*)d_in[1];
    const float* p4    = (const float*)d_in[2];
    const float* p5    = (const float*)d_in[3];
    const float* boxes = (const float*)d_in[4];
    const int*   bidx  = (const int*)d_in[5];
    float* out = (float*)d_out;
    int N = in_sizes[5];
    dim3 grid(N, CH_SPLIT);
    roi_align_fpn_kernel<<<grid, 256, 0, stream>>>(p2, p3, p4, p5, boxes, bidx, out, N);
}